// Round 1
// baseline (5530.785 us; speedup 1.0000x reference)
//
#include <hip/hip_runtime.h>
#include <math.h>

// Problem constants (B=2, S=2048, d=1024, h=8, hd=128, hv=256, vd=2048, f=4096)
#define RTOT 4096   // B*S rows
#define SEQ  2048
#define DMODEL 1024
#define NH   8
#define HD   128
#define HV   256
#define VD   2048
#define FF   4096

// ---------------- LayerNorm: one block per row of 1024 ----------------
__global__ __launch_bounds__(256) void ln_kernel(const float* __restrict__ x,
    const float* __restrict__ w, const float* __restrict__ b,
    float* __restrict__ out) {
  int row = blockIdx.x, tid = threadIdx.x;
  const float* xr = x + (long)row * DMODEL;
  float4 v = *(const float4*)(xr + tid * 4);
  float s  = v.x + v.y + v.z + v.w;
  float ss = v.x*v.x + v.y*v.y + v.z*v.z + v.w*v.w;
  #pragma unroll
  for (int o = 32; o > 0; o >>= 1) { s += __shfl_down(s, o); ss += __shfl_down(ss, o); }
  __shared__ float red[2][4];
  int wid = tid >> 6;
  if ((tid & 63) == 0) { red[0][wid] = s; red[1][wid] = ss; }
  __syncthreads();
  float st  = red[0][0] + red[0][1] + red[0][2] + red[0][3];
  float sst = red[1][0] + red[1][1] + red[1][2] + red[1][3];
  float mu   = st * (1.f / DMODEL);
  float var  = sst * (1.f / DMODEL) - mu * mu;
  float rstd = rsqrtf(var + 1e-5f);
  float4 wv = *(const float4*)(w + tid * 4);
  float4 bv = *(const float4*)(b + tid * 4);
  float4 o4;
  o4.x = (v.x - mu) * rstd * wv.x + bv.x;
  o4.y = (v.y - mu) * rstd * wv.y + bv.y;
  o4.z = (v.z - mu) * rstd * wv.z + bv.z;
  o4.w = (v.w - mu) * rstd * wv.w + bv.w;
  *(float4*)(out + (long)row * DMODEL + tid * 4) = o4;
}

// ---------------- Generic 64x64 f32 GEMM, batched via grid.z ----------------
// C[m,n] = sum_k A[m,k]*B[k,n]  (+bias)(+gelu)(+resid). All dims multiples of 64/16.
__global__ __launch_bounds__(256) void gemm64(
    const float* __restrict__ A, int lda, long sA,
    const float* __restrict__ Bm, int ldb, long sB,
    float* __restrict__ C, int ldc, long sC,
    int K, const float* __restrict__ bias,
    const float* __restrict__ resid, int gelu_flag) {
  int z = blockIdx.z;
  A  += (long)z * sA;
  Bm += (long)z * sB;
  C  += (long)z * sC;
  __shared__ float As[16][68];   // [k][m], +4 pad
  __shared__ float Bs[16][68];   // [k][n], +4 pad
  int tx = threadIdx.x, ty = threadIdx.y;
  int tid = ty * 16 + tx;
  int m0 = blockIdx.y * 64, n0 = blockIdx.x * 64;
  int amm = tid >> 2, akq = (tid & 3) * 4;
  int bkk = tid >> 4, bnn = (tid & 15) * 4;
  const float* Aptr = A + (long)(m0 + amm) * lda + akq;
  const float* Bptr = Bm + (long)bkk * ldb + n0 + bnn;
  float acc[4][4] = {};
  for (int k0 = 0; k0 < K; k0 += 16) {
    float4 av = *(const float4*)(Aptr + k0);
    float4 bv = *(const float4*)(Bptr + (long)k0 * ldb);
    As[akq + 0][amm] = av.x; As[akq + 1][amm] = av.y;
    As[akq + 2][amm] = av.z; As[akq + 3][amm] = av.w;
    *(float4*)&Bs[bkk][bnn] = bv;
    __syncthreads();
    #pragma unroll
    for (int kk = 0; kk < 16; ++kk) {
      float4 a = *(const float4*)&As[kk][ty * 4];
      float4 b = *(const float4*)&Bs[kk][tx * 4];
      acc[0][0] += a.x*b.x; acc[0][1] += a.x*b.y; acc[0][2] += a.x*b.z; acc[0][3] += a.x*b.w;
      acc[1][0] += a.y*b.x; acc[1][1] += a.y*b.y; acc[1][2] += a.y*b.z; acc[1][3] += a.y*b.w;
      acc[2][0] += a.z*b.x; acc[2][1] += a.z*b.y; acc[2][2] += a.z*b.z; acc[2][3] += a.z*b.w;
      acc[3][0] += a.w*b.x; acc[3][1] += a.w*b.y; acc[3][2] += a.w*b.z; acc[3][3] += a.w*b.w;
    }
    __syncthreads();
  }
  #pragma unroll
  for (int i = 0; i < 4; ++i) {
    long m = m0 + ty * 4 + i;
    int  n = n0 + tx * 4;
    float vv[4];
    #pragma unroll
    for (int j = 0; j < 4; ++j) {
      float v = acc[i][j];
      if (bias) v += bias[n + j];
      if (gelu_flag) v = 0.5f * v * (1.f + erff(v * 0.70710678f));  // exact GELU
      if (resid) v += resid[m * ldc + n + j];
      vv[j] = v;
    }
    *(float4*)(C + m * ldc + n) = make_float4(vv[0], vv[1], vv[2], vv[3]);
  }
}

// ---------------- xpos rotary + scale, in place on (h, R, 128) ----------------
__global__ __launch_bounds__(256) void xpos_kernel(float* __restrict__ q, int downscale) {
  int idx = blockIdx.x * 256 + threadIdx.x;   // one thread per (row, pair)
  int j   = idx & 63;                          // pair index 0..63
  int row = (idx >> 6) & (RTOT - 1);           // b*S + s
  int pos = row & (SEQ - 1);                   // s
  float bs = (2.f * (float)j + 51.2f) * (1.f / 179.2f);   // (2j + 0.4*128)/(1.4*128)
  float ex = (float)pos * (1.f / 512.f);
  if (downscale) ex = -ex;
  float scale = exp2f(ex * log2f(bs));
  float inv_freq = exp2f((float)j * (-13.287712379549449f / 64.f));  // 10000^(-j/64)
  float sinu = (float)pos * inv_freq;
  float sv, cv;
  sincosf(sinu, &sv, &cv);
  sv *= scale; cv *= scale;
  float2 xv = ((float2*)q)[idx];
  float2 o;
  o.x = xv.x * cv - xv.y * sv;
  o.y = xv.y * cv + xv.x * sv;
  ((float2*)q)[idx] = o;
}

// ---------------- Fused retention core: Y = (QK^T * D) V, causal decay ------
// grid(S/16, NH, B), block 256. Per block: 16 q-rows x 256 v-cols accumulator.
__global__ __launch_bounds__(256) void retention_kernel(
    const float* __restrict__ Q, const float* __restrict__ K,
    const float* __restrict__ V, float* __restrict__ Y) {
  __shared__ float Qs[16][132], Ks[16][132], Vs[16][256], Ss[16][17];
  int qt = blockIdx.x, h = blockIdx.y, b = blockIdx.z;
  int q0 = qt * 16;
  int tid = threadIdx.x;
  int tx = tid & 15, ty = tid >> 4;
  // gammas = 1 - exp(linspace(log(1/32), log(1/512), 8))
  float gamma = 1.f - expf(-3.4657359028f - 0.3960841032f * (float)h);
  float lg = logf(gamma);
  long base = (long)h * RTOT + (long)b * SEQ;
  { // load Q tile once
    int i = tid >> 4, e0 = (tid & 15) * 8;
    const float* src = Q + (base + q0 + i) * HD + e0;
    *(float4*)&Qs[i][e0]     = *(const float4*)src;
    *(float4*)&Qs[i][e0 + 4] = *(const float4*)(src + 4);
  }
  float acc[16];
  #pragma unroll
  for (int c = 0; c < 16; ++c) acc[c] = 0.f;
  // skip tiles whose max decay < e^-30 (contribution < 1e-10)
  int cutoff  = (int)(30.f / (-lg));
  int t_start = q0 - 15 - cutoff;
  if (t_start < 0) t_start = 0;
  t_start &= ~15;
  for (int t0 = t_start; t0 <= q0; t0 += 16) {
    __syncthreads();
    { // stage K,V tiles
      int j = tid >> 4, e0 = (tid & 15) * 8;
      const float* ksrc = K + (base + t0 + j) * HD + e0;
      *(float4*)&Ks[j][e0]     = *(const float4*)ksrc;
      *(float4*)&Ks[j][e0 + 4] = *(const float4*)(ksrc + 4);
      int c0 = (tid & 15) * 16;
      const float* vsrc = V + (base + t0 + j) * HV + c0;
      *(float4*)&Vs[j][c0]      = *(const float4*)vsrc;
      *(float4*)&Vs[j][c0 + 4]  = *(const float4*)(vsrc + 4);
      *(float4*)&Vs[j][c0 + 8]  = *(const float4*)(vsrc + 8);
      *(float4*)&Vs[j][c0 + 12] = *(const float4*)(vsrc + 12);
    }
    __syncthreads();
    // scores
    float s = 0.f;
    #pragma unroll
    for (int e = 0; e < HD; e += 4) {
      float4 qv = *(const float4*)&Qs[ty][e];
      float4 kv = *(const float4*)&Ks[tx][e];
      s += qv.x*kv.x + qv.y*kv.y + qv.z*kv.z + qv.w*kv.w;
    }
    int diff = (q0 + ty) - (t0 + tx);
    s = (diff >= 0) ? s * expf((float)diff * lg) : 0.f;
    Ss[ty][tx] = s;
    __syncthreads();
    // PV accumulate: row ty, cols c*16+tx
    #pragma unroll
    for (int j = 0; j < 16; ++j) {
      float sv = Ss[ty][j];
      #pragma unroll
      for (int c = 0; c < 16; ++c)
        acc[c] += sv * Vs[j][c * 16 + tx];
    }
  }
  float* yr = Y + (base + q0 + ty) * HV;
  #pragma unroll
  for (int c = 0; c < 16; ++c) yr[c * 16 + tx] = acc[c];
}

// ---------------- GroupNorm(Y over hv) * gn affine * SiLU(gate), into G -----
// blockIdx = (b*S+s)*8 + h, 64 threads (one wave), 4 elems each.
__global__ __launch_bounds__(64) void combine_kernel(
    const float* __restrict__ Y, float* __restrict__ G,
    const float* __restrict__ gw, const float* __restrict__ gb) {
  int blk = blockIdx.x;
  int h = blk & 7;
  int row = blk >> 3;                 // b*S + s
  int lane = threadIdx.x;
  const float* yr = Y + ((long)h * RTOT + row) * HV;
  float4 yv = *(const float4*)(yr + lane * 4);
  float s  = yv.x + yv.y + yv.z + yv.w;
  float ss = yv.x*yv.x + yv.y*yv.y + yv.z*yv.z + yv.w*yv.w;
  #pragma unroll
  for (int o = 32; o > 0; o >>= 1) { s += __shfl_xor(s, o); ss += __shfl_xor(ss, o); }
  float mu   = s * (1.f / HV);
  float var  = ss * (1.f / HV) - mu * mu;
  float rstd = rsqrtf(var + 1e-5f);
  int gi = h * HV + lane * 4;
  long gidx = (long)row * VD + gi;
  float4 gv = *(const float4*)(G + gidx);
  float4 wv = *(const float4*)(gw + gi);
  float4 bv = *(const float4*)(gb + gi);
  float4 o4;
  o4.x = (gv.x / (1.f + expf(-gv.x))) * ((yv.x - mu) * rstd * wv.x + bv.x);
  o4.y = (gv.y / (1.f + expf(-gv.y))) * ((yv.y - mu) * rstd * wv.y + bv.y);
  o4.z = (gv.z / (1.f + expf(-gv.z))) * ((yv.z - mu) * rstd * wv.z + bv.z);
  o4.w = (gv.w / (1.f + expf(-gv.w))) * ((yv.w - mu) * rstd * wv.w + bv.w);
  *(float4*)(G + gidx) = o4;
}

extern "C" void kernel_launch(void* const* d_in, const int* in_sizes, int n_in,
                              void* d_out, int out_size, void* d_ws, size_t ws_size,
                              hipStream_t stream) {
  const float* X    = (const float*)d_in[0];
  const float* mem  = (const float*)d_in[1];
  const float* ln1w = (const float*)d_in[2];
  const float* ln1b = (const float*)d_in[3];
  const float* ln2w = (const float*)d_in[4];
  const float* ln2b = (const float*)d_in[5];
  const float* Wq   = (const float*)d_in[6];
  const float* Wk   = (const float*)d_in[7];
  const float* Wv   = (const float*)d_in[8];
  const float* Wg   = (const float*)d_in[9];
  const float* Wo   = (const float*)d_in[10];
  const float* gnw  = (const float*)d_in[11];
  const float* gnb  = (const float*)d_in[12];
  const float* cWq  = (const float*)d_in[13];
  const float* cWk  = (const float*)d_in[14];
  const float* cWv  = (const float*)d_in[15];
  const float* cWg  = (const float*)d_in[16];
  const float* cWo  = (const float*)d_in[17];
  const float* cgnw = (const float*)d_in[18];
  const float* cgnb = (const float*)d_in[19];
  const float* W1   = (const float*)d_in[20];
  const float* b1   = (const float*)d_in[21];
  const float* W2   = (const float*)d_in[22];
  const float* b2   = (const float*)d_in[23];
  float* out = (float*)d_out;
  float* ws  = (float*)d_ws;

  // workspace layout (float offsets): h 4M | Q 4M | K 4M | V 8M | Y 8M  = 28M floats
  if (ws_size < (28ull << 20) * sizeof(float)) return;  // need 112 MB scratch
  float* hbuf = ws;
  float* Qb = ws + (4ull  << 20);
  float* Kb = ws + (8ull  << 20);
  float* Vb = ws + (12ull << 20);
  float* Yb = ws + (20ull << 20);
  float* Gb = Qb;   // reuses Q+K region after retention consumed them (8M floats)
  float* Tb = Qb;   // FFN intermediate reuses Q+K+V region (16M floats)

  dim3 gB(16, 16);

  auto run_ret = [&](const float* xq, const float* xkv,
                     const float* wq, const float* wk, const float* wv,
                     const float* wg, const float* wo,
                     const float* gw, const float* gb_,
                     const float* resid, float* cout) {
    gemm64<<<dim3(HD / 64, RTOT / 64, NH), gB, 0, stream>>>(
        xq, DMODEL, 0, wq, HD, (long)DMODEL * HD, Qb, HD, (long)RTOT * HD,
        DMODEL, nullptr, nullptr, 0);
    gemm64<<<dim3(HD / 64, RTOT / 64, NH), gB, 0, stream>>>(
        xkv, DMODEL, 0, wk, HD, (long)DMODEL * HD, Kb, HD, (long)RTOT * HD,
        DMODEL, nullptr, nullptr, 0);
    gemm64<<<dim3(HV / 64, RTOT / 64, NH), gB, 0, stream>>>(
        xkv, DMODEL, 0, wv, HV, (long)DMODEL * HV, Vb, HV, (long)RTOT * HV,
        DMODEL, nullptr, nullptr, 0);
    xpos_kernel<<<(NH * RTOT * 64) / 256, 256, 0, stream>>>(Qb, 0);
    xpos_kernel<<<(NH * RTOT * 64) / 256, 256, 0, stream>>>(Kb, 1);
    retention_kernel<<<dim3(SEQ / 16, NH, 2), 256, 0, stream>>>(Qb, Kb, Vb, Yb);
    gemm64<<<dim3(VD / 64, RTOT / 64, 1), gB, 0, stream>>>(
        xq, DMODEL, 0, wg, VD, 0, Gb, VD, 0, DMODEL, nullptr, nullptr, 0);
    combine_kernel<<<RTOT * NH, 64, 0, stream>>>(Yb, Gb, gw, gb_);
    gemm64<<<dim3(DMODEL / 64, RTOT / 64, 1), gB, 0, stream>>>(
        Gb, VD, 0, wo, DMODEL, 0, cout, DMODEL, 0, VD, nullptr, resid, 0);
  };

  // Block 1: self retention on LN1(X), residual X -> out
  ln_kernel<<<RTOT, 256, 0, stream>>>(X, ln1w, ln1b, hbuf);
  run_ret(hbuf, hbuf, Wq, Wk, Wv, Wg, Wo, gnw, gnb, X, out);

  // Block 2: cross retention, Q from LN2(out), K/V from raw mem, residual out
  ln_kernel<<<RTOT, 256, 0, stream>>>(out, ln2w, ln2b, hbuf);
  run_ret(hbuf, mem, cWq, cWk, cWv, cWg, cWo, cgnw, cgnb, out, out);

  // FFN: LN2(out) -> GELU(W1+b1) -> W2+b2 + out
  ln_kernel<<<RTOT, 256, 0, stream>>>(out, ln2w, ln2b, hbuf);
  gemm64<<<dim3(FF / 64, RTOT / 64, 1), gB, 0, stream>>>(
      hbuf, DMODEL, 0, W1, FF, 0, Tb, FF, 0, DMODEL, b1, nullptr, 1);
  gemm64<<<dim3(DMODEL / 64, RTOT / 64, 1), gB, 0, stream>>>(
      Tb, FF, 0, W2, DMODEL, 0, out, DMODEL, 0, FF, b2, out, 0);
}

// Round 2
// 749.278 us; speedup vs baseline: 7.3815x; 7.3815x over previous
//
#include <hip/hip_runtime.h>
#include <math.h>

// Problem: B=2, S=2048, d=1024, h=8, hd=128, hv=256, vd=2048, f=4096
#define RTOT 4096
#define SEQQ 2048

typedef unsigned int uint32;
typedef __attribute__((ext_vector_type(4))) float f32x4;
typedef __attribute__((ext_vector_type(8))) short bf16x8;

__device__ __forceinline__ unsigned short f2bf(float f) {
  unsigned int u = __float_as_uint(f);
  u = (u + 0x7FFFu + ((u >> 16) & 1u)) >> 16;
  return (unsigned short)u;
}
__device__ __forceinline__ float bf2f(unsigned short h) {
  return __uint_as_float(((unsigned int)h) << 16);
}
__device__ __forceinline__ void gld16(const void* g, void* l) {
  __builtin_amdgcn_global_load_lds(
      (const __attribute__((address_space(1))) uint32*)g,
      (__attribute__((address_space(3))) uint32*)l, 16, 0, 0);
}

// ---------------- tiled transpose f32[R][C] -> bf16[C][R], batched z ----------
__global__ __launch_bounds__(256) void transpose_bf16(
    const float* __restrict__ in, unsigned short* __restrict__ out, int R, int C) {
  __shared__ float t[32][33];
  int z = blockIdx.z;
  in  += (size_t)z * R * C;
  out += (size_t)z * C * R;
  int r0 = blockIdx.x * 32, c0 = blockIdx.y * 32;
  int tx = threadIdx.x & 31, ty = threadIdx.x >> 5;
  #pragma unroll
  for (int i = 0; i < 4; ++i) {
    int r = ty + i * 8;
    t[r][tx] = in[(size_t)(r0 + r) * C + c0 + tx];
  }
  __syncthreads();
  #pragma unroll
  for (int i = 0; i < 4; ++i) {
    int c = ty + i * 8;
    out[(size_t)(c0 + c) * R + r0 + tx] = f2bf(t[tx][c]);
  }
}

// ---------------- f32 -> bf16 convert ----------------
__global__ __launch_bounds__(256) void cvt_bf16(
    const float* __restrict__ in, unsigned short* __restrict__ out, int n8) {
  int i = blockIdx.x * 256 + threadIdx.x;
  if (i >= n8) return;
  const float4* p = (const float4*)(in + (size_t)i * 8);
  float4 a = p[0], b = p[1];
  bf16x8 v;
  v[0] = (short)f2bf(a.x); v[1] = (short)f2bf(a.y); v[2] = (short)f2bf(a.z); v[3] = (short)f2bf(a.w);
  v[4] = (short)f2bf(b.x); v[5] = (short)f2bf(b.y); v[6] = (short)f2bf(b.z); v[7] = (short)f2bf(b.w);
  *(bf16x8*)(out + (size_t)i * 8) = v;
}

// ---------------- xpos coefficient tables [4][2048*64] f32 -------------------
__global__ __launch_bounds__(256) void tabgen(float* __restrict__ tab) {
  int i = blockIdx.x * 256 + threadIdx.x;   // 131072
  int pos = i >> 6, j = i & 63;
  float bs = (2.f * (float)j + 51.2f) * (1.f / 179.2f);
  float e = (float)pos * (1.f / 512.f);
  float sc = exp2f(e * log2f(bs));                       // base_scale^(pos/512)
  float invf = exp2f(-(float)j * (13.287712379549449f / 64.f));
  float su, cu;
  sincosf((float)pos * invf, &su, &cu);
  tab[i]            = cu * sc;   // cosQ
  tab[131072 + i]   = su * sc;   // sinQ
  float si = 1.f / sc;
  tab[262144 + i]   = cu * si;   // cosK
  tab[393216 + i]   = su * si;   // sinK
}

// ---------------- LayerNorm -> bf16 ----------------
__global__ __launch_bounds__(256) void ln_bf16(const float* __restrict__ x,
    const float* __restrict__ w, const float* __restrict__ b,
    unsigned short* __restrict__ out) {
  int row = blockIdx.x, tid = threadIdx.x;
  const float* xr = x + (size_t)row * 1024;
  float4 v = *(const float4*)(xr + tid * 4);
  float s  = v.x + v.y + v.z + v.w;
  float ss = v.x*v.x + v.y*v.y + v.z*v.z + v.w*v.w;
  #pragma unroll
  for (int o = 32; o > 0; o >>= 1) { s += __shfl_down(s, o); ss += __shfl_down(ss, o); }
  __shared__ float red[2][4];
  int wid = tid >> 6;
  if ((tid & 63) == 0) { red[0][wid] = s; red[1][wid] = ss; }
  __syncthreads();
  float st  = red[0][0] + red[0][1] + red[0][2] + red[0][3];
  float sst = red[1][0] + red[1][1] + red[1][2] + red[1][3];
  float mu   = st * (1.f / 1024.f);
  float var  = sst * (1.f / 1024.f) - mu * mu;
  float rstd = rsqrtf(var + 1e-5f);
  float4 wv = *(const float4*)(w + tid * 4);
  float4 bv = *(const float4*)(b + tid * 4);
  unsigned short o0 = f2bf((v.x - mu) * rstd * wv.x + bv.x);
  unsigned short o1 = f2bf((v.y - mu) * rstd * wv.y + bv.y);
  unsigned short o2 = f2bf((v.z - mu) * rstd * wv.z + bv.z);
  unsigned short o3 = f2bf((v.w - mu) * rstd * wv.w + bv.w);
  ushort4 o4 = make_ushort4(o0, o1, o2, o3);
  *(ushort4*)(out + (size_t)row * 1024 + tid * 4) = o4;
}

// ---------------- MFMA GEMM: C[M][N] = A[M][K] * Bt[N][K]^T, 128x128 tile ----
enum { EPI_F32_RES = 0, EPI_BF16 = 1, EPI_XPOS = 2, EPI_GATE = 3, EPI_GELU = 4, EPI_BRES = 5 };

template<int EPI>
__global__ __launch_bounds__(256) void gemm_mfma(
    const unsigned short* __restrict__ A, int lda,
    const unsigned short* __restrict__ Bt, int ldb,
    void* __restrict__ Cv, int ldc, int K,
    const float* __restrict__ bias, const float* __restrict__ resid,
    const float* __restrict__ tc, const float* __restrict__ ts) {
  __shared__ __align__(16) unsigned short As[128 * 32];
  __shared__ __align__(16) unsigned short Bs[128 * 32];
  const int tid = threadIdx.x, w = tid >> 6, lane = tid & 63;
  const int M0 = blockIdx.y * 128, N0 = blockIdx.x * 128;
  const int fr = lane & 15, fs = lane >> 4;
  const int srow = lane >> 2, sp = lane & 3;

  f32x4 zf = {0.f, 0.f, 0.f, 0.f};
  f32x4 acc[4][4];
  #pragma unroll
  for (int i = 0; i < 4; ++i)
    #pragma unroll
    for (int j = 0; j < 4; ++j) acc[i][j] = zf;

  for (int k0 = 0; k0 < K; k0 += 32) {
    __syncthreads();
    #pragma unroll
    for (int c = 0; c < 4; ++c) {
      int ch = w * 4 + c;
      int cc = ch & 7;
      int row = cc * 16 + srow;
      int so = sp ^ ((row >> 1) & 3);
      if (ch < 8) gld16(A  + (size_t)(M0 + row) * lda + k0 + so * 8, As + cc * 512);
      else        gld16(Bt + (size_t)(N0 + row) * ldb + k0 + so * 8, Bs + cc * 512);
    }
    __syncthreads();
    bf16x8 af[4], bf[4];
    #pragma unroll
    for (int mi = 0; mi < 4; ++mi) {
      int row = (w >> 1) * 64 + mi * 16 + fr;
      af[mi] = *(const bf16x8*)(As + row * 32 + (fs ^ ((row >> 1) & 3)) * 8);
    }
    #pragma unroll
    for (int ni = 0; ni < 4; ++ni) {
      int row = (w & 1) * 64 + ni * 16 + fr;
      bf[ni] = *(const bf16x8*)(Bs + row * 32 + (fs ^ ((row >> 1) & 3)) * 8);
    }
    #pragma unroll
    for (int mi = 0; mi < 4; ++mi)
      #pragma unroll
      for (int ni = 0; ni < 4; ++ni)
        acc[mi][ni] = __builtin_amdgcn_mfma_f32_16x16x32_bf16(af[mi], bf[ni], acc[mi][ni], 0, 0, 0);
  }

  float* Cf = (float*)Cv;
  unsigned short* Cb = (unsigned short*)Cv;
  #pragma unroll
  for (int mi = 0; mi < 4; ++mi) {
    #pragma unroll
    for (int r = 0; r < 4; ++r) {
      size_t m = M0 + (w >> 1) * 64 + mi * 16 + fs * 4 + r;
      #pragma unroll
      for (int ni = 0; ni < 4; ++ni) {
        int n = N0 + (w & 1) * 64 + ni * 16 + fr;
        float v = acc[mi][ni][r];
        if constexpr (EPI == EPI_XPOS) {
          float p = __shfl_xor(v, 1);
          int j = (n & 127) >> 1;
          int pos = (int)(m & (SEQQ - 1));
          float c = tc[pos * 64 + j], s = ts[pos * 64 + j];
          v = (n & 1) ? (v * c + p * s) : (v * c - p * s);
          Cb[m * ldc + n] = f2bf(v);
        } else if constexpr (EPI == EPI_BF16) {
          Cb[m * ldc + n] = f2bf(v);
        } else if constexpr (EPI == EPI_GATE) {
          Cb[m * ldc + n] = f2bf(v / (1.f + expf(-v)));
        } else if constexpr (EPI == EPI_GELU) {
          v += bias[n];
          v = 0.5f * v * (1.f + erff(v * 0.70710678f));
          Cb[m * ldc + n] = f2bf(v);
        } else if constexpr (EPI == EPI_BRES) {
          v += bias[n] + resid[m * ldc + n];
          Cf[m * ldc + n] = v;
        } else {
          v += resid[m * ldc + n];
          Cf[m * ldc + n] = v;
        }
      }
    }
  }
}

// ---------------- MFMA retention: Y=(QK^T*D)V fused with groupnorm+gate -----
// grid(32 qtiles, 8 heads, 2 batch), 4 waves; wave w owns q rows q0+16w..+15.
__global__ __launch_bounds__(256) void retention_mfma(
    const unsigned short* __restrict__ Qx, const unsigned short* __restrict__ Kx,
    const unsigned short* __restrict__ VT, const unsigned short* __restrict__ Gate,
    const float* __restrict__ gnw, const float* __restrict__ gnb,
    unsigned short* __restrict__ Gout) {
  __shared__ __align__(16) unsigned short Ks[32 * 128];   // [32 t][128 e], 16-slot swz
  __shared__ __align__(16) unsigned short Vs[256 * 32];   // [256 v][32 t], 4-slot swz
  __shared__ __align__(16) float Ps[4][16 * 36];          // per-wave P 16x32, stride 36
  const int tid = threadIdx.x, w = tid >> 6, lane = tid & 63;
  const int q0 = blockIdx.x * 64, h = blockIdx.y, b = blockIdx.z;
  const int fr = lane & 15, fs = lane >> 4;

  float gamma = 1.f - expf(-3.4657359028f - 0.3960841032f * (float)h);
  float l2g = log2f(gamma);     // negative

  size_t qrow = (size_t)b * SEQQ + q0 + w * 16 + fr;
  bf16x8 qf[4];
  #pragma unroll
  for (int ks = 0; ks < 4; ++ks)
    qf[ks] = *(const bf16x8*)(Qx + qrow * 1024 + h * 128 + ks * 32 + fs * 8);

  f32x4 zf = {0.f, 0.f, 0.f, 0.f};
  f32x4 yacc[16];
  #pragma unroll
  for (int i = 0; i < 16; ++i) yacc[i] = zf;

  int cutoff = (int)(27.f / (-l2g));   // decay < 2^-27: negligible vs bf16 P
  int t_start = q0 - cutoff;
  if (t_start < 0) t_start = 0;
  t_start &= ~31;
  size_t kbase = (size_t)b * SEQQ;

  for (int t0 = t_start; t0 < q0 + 64; t0 += 32) {
    __syncthreads();
    #pragma unroll
    for (int c = 0; c < 2; ++c) {          // K tile: 8 chunks of 4 rows x 256B
      int ch = w * 2 + c;
      int row = ch * 4 + (lane >> 4);
      int so = (lane & 15) ^ (row & 15);
      gld16(Kx + (kbase + t0 + row) * 1024 + h * 128 + so * 8, Ks + ch * 512);
    }
    #pragma unroll
    for (int c = 0; c < 4; ++c) {          // V^T tile: 16 chunks of 16 rows x 64B
      int ch = w * 4 + c;
      int vrow = ch * 16 + (lane >> 2);
      int so = (lane & 3) ^ ((vrow >> 1) & 3);
      gld16(VT + (size_t)(h * 256 + vrow) * RTOT + kbase + t0 + so * 8, Vs + ch * 512);
    }
    __syncthreads();

    // S = Q K^T  (16 q x 32 t per wave)
    f32x4 sacc[2];
    sacc[0] = zf; sacc[1] = zf;
    #pragma unroll
    for (int nt = 0; nt < 2; ++nt) {
      int row = nt * 16 + fr;
      #pragma unroll
      for (int ks = 0; ks < 4; ++ks) {
        int sl = ks * 4 + fs;
        bf16x8 kf = *(const bf16x8*)(Ks + row * 128 + (sl ^ (row & 15)) * 8);
        sacc[nt] = __builtin_amdgcn_mfma_f32_16x16x32_bf16(qf[ks], kf, sacc[nt], 0, 0, 0);
      }
    }
    // decay + causal mask, write P to per-wave LDS
    float* Pw = Ps[w];
    #pragma unroll
    for (int nt = 0; nt < 2; ++nt) {
      #pragma unroll
      for (int r = 0; r < 4; ++r) {
        int sl_ = fs * 4 + r;
        int diff = (q0 + w * 16 + sl_) - (t0 + nt * 16 + fr);
        float v = (diff >= 0) ? sacc[nt][r] * exp2f((float)diff * l2g) : 0.f;
        Pw[sl_ * 36 + nt * 16 + fr] = v;
      }
    }
    // re-fragment P as MFMA A operand (row = fr, k = fs*8..+7), convert bf16
    f32x4 pa = *(const f32x4*)(Pw + fr * 36 + fs * 8);
    f32x4 pb = *(const f32x4*)(Pw + fr * 36 + fs * 8 + 4);
    bf16x8 pf;
    pf[0] = (short)f2bf(pa[0]); pf[1] = (short)f2bf(pa[1]);
    pf[2] = (short)f2bf(pa[2]); pf[3] = (short)f2bf(pa[3]);
    pf[4] = (short)f2bf(pb[0]); pf[5] = (short)f2bf(pb[1]);
    pf[6] = (short)f2bf(pb[2]); pf[7] = (short)f2bf(pb[3]);
    // Y += P V
    #pragma unroll
    for (int nv = 0; nv < 16; ++nv) {
      int vrow = nv * 16 + fr;
      bf16x8 vf = *(const bf16x8*)(Vs + vrow * 32 + (fs ^ ((vrow >> 1) & 3)) * 8);
      yacc[nv] = __builtin_amdgcn_mfma_f32_16x16x32_bf16(pf, vf, yacc[nv], 0, 0, 0);
    }
  }

  // epilogue: per-row groupnorm over 256 v, * gn affine, * silu gate, -> bf16
  #pragma unroll
  for (int r = 0; r < 4; ++r) {
    float s = 0.f, sq = 0.f;
    #pragma unroll
    for (int nv = 0; nv < 16; ++nv) { float v = yacc[nv][r]; s += v; sq += v * v; }
    #pragma unroll
    for (int msk = 1; msk < 16; msk <<= 1) { s += __shfl_xor(s, msk); sq += __shfl_xor(sq, msk); }
    float mu = s * (1.f / 256.f);
    float var = sq * (1.f / 256.f) - mu * mu;
    float rstd = rsqrtf(var + 1e-5f);
    int srow = q0 + w * 16 + fs * 4 + r;
    size_t mrow = (size_t)b * SEQQ + srow;
    const unsigned short* grow = Gate + mrow * 2048 + h * 256;
    unsigned short* orow = Gout + mrow * 2048 + h * 256;
    #pragma unroll
    for (int nv = 0; nv < 16; ++nv) {
      int col = nv * 16 + fr;
      float yn = (yacc[nv][r] - mu) * rstd * gnw[h * 256 + col] + gnb[h * 256 + col];
      orow[col] = f2bf(bf2f(grow[col]) * yn);
    }
  }
}

// =============================== host ========================================
extern "C" void kernel_launch(void* const* d_in, const int* in_sizes, int n_in,
                              void* d_out, int out_size, void* d_ws, size_t ws_size,
                              hipStream_t stream) {
  const float* X    = (const float*)d_in[0];
  const float* mem  = (const float*)d_in[1];
  const float* ln1w = (const float*)d_in[2];
  const float* ln1b = (const float*)d_in[3];
  const float* ln2w = (const float*)d_in[4];
  const float* ln2b = (const float*)d_in[5];
  const float* Wq   = (const float*)d_in[6];
  const float* Wk   = (const float*)d_in[7];
  const float* Wv   = (const float*)d_in[8];
  const float* Wg   = (const float*)d_in[9];
  const float* Wo   = (const float*)d_in[10];
  const float* gnw  = (const float*)d_in[11];
  const float* gnb  = (const float*)d_in[12];
  const float* cWq  = (const float*)d_in[13];
  const float* cWk  = (const float*)d_in[14];
  const float* cWv  = (const float*)d_in[15];
  const float* cWg  = (const float*)d_in[16];
  const float* cWo  = (const float*)d_in[17];
  const float* cgnw = (const float*)d_in[18];
  const float* cgnb = (const float*)d_in[19];
  const float* W1   = (const float*)d_in[20];
  const float* b1   = (const float*)d_in[21];
  const float* W2   = (const float*)d_in[22];
  const float* b2   = (const float*)d_in[23];
  float* out = (float*)d_out;

  const size_t MB = 1024ull * 1024ull;
  if (ws_size < 106 * MB) return;
  unsigned char* W8 = (unsigned char*)d_ws;
  unsigned short* WqT  = (unsigned short*)(W8 + 0 * MB);
  unsigned short* WkT  = (unsigned short*)(W8 + 2 * MB);
  unsigned short* WvT  = (unsigned short*)(W8 + 4 * MB);
  unsigned short* WgT  = (unsigned short*)(W8 + 8 * MB);
  unsigned short* WoT  = (unsigned short*)(W8 + 12 * MB);
  unsigned short* cWqT = (unsigned short*)(W8 + 16 * MB);
  unsigned short* cWkT = (unsigned short*)(W8 + 18 * MB);
  unsigned short* cWvT = (unsigned short*)(W8 + 20 * MB);
  unsigned short* cWgT = (unsigned short*)(W8 + 24 * MB);
  unsigned short* cWoT = (unsigned short*)(W8 + 28 * MB);
  float*          tab  = (float*)(W8 + 32 * MB);           // 2MB
  unsigned short* hbuf = (unsigned short*)(W8 + 34 * MB);  // 8MB
  unsigned short* Qx   = (unsigned short*)(W8 + 42 * MB);  // 8MB (later W1T)
  unsigned short* Kx   = (unsigned short*)(W8 + 50 * MB);  // 8MB (later W2T)
  unsigned short* W1T  = Qx;
  unsigned short* W2T  = Kx;
  unsigned short* VTb  = (unsigned short*)(W8 + 58 * MB);  // 16MB
  unsigned short* Gg   = (unsigned short*)(W8 + 74 * MB);  // 16MB
  unsigned short* Tb   = VTb;                               // FFN mid 32MB (VT+Gg)
  unsigned short* GoutB= (unsigned short*)(W8 + 90 * MB);  // 16MB
  unsigned short* mem16= GoutB;                             // 8MB, dead-window overlay

  const float* tcQ = tab, *tsQ = tab + 131072, *tcK = tab + 262144, *tsK = tab + 393216;

  // weight prep
  transpose_bf16<<<dim3(32, 4, 8),  256, 0, stream>>>(Wq,  WqT,  1024, 128);
  transpose_bf16<<<dim3(32, 4, 8),  256, 0, stream>>>(Wk,  WkT,  1024, 128);
  transpose_bf16<<<dim3(32, 8, 8),  256, 0, stream>>>(Wv,  WvT,  1024, 256);
  transpose_bf16<<<dim3(32, 64, 1), 256, 0, stream>>>(Wg,  WgT,  1024, 2048);
  transpose_bf16<<<dim3(64, 32, 1), 256, 0, stream>>>(Wo,  WoT,  2048, 1024);
  transpose_bf16<<<dim3(32, 4, 8),  256, 0, stream>>>(cWq, cWqT, 1024, 128);
  transpose_bf16<<<dim3(32, 4, 8),  256, 0, stream>>>(cWk, cWkT, 1024, 128);
  transpose_bf16<<<dim3(32, 8, 8),  256, 0, stream>>>(cWv, cWvT, 1024, 256);
  transpose_bf16<<<dim3(32, 64, 1), 256, 0, stream>>>(cWg, cWgT, 1024, 2048);
  transpose_bf16<<<dim3(64, 32, 1), 256, 0, stream>>>(cWo, cWoT, 2048, 1024);
  tabgen<<<512, 256, 0, stream>>>(tab);

  // ---- block 1: self retention ----
  ln_bf16<<<RTOT, 256, 0, stream>>>(X, ln1w, ln1b, hbuf);
  gemm_mfma<EPI_XPOS><<<dim3(8, 32), 256, 0, stream>>>(hbuf, 1024, WqT, 1024, Qx, 1024, 1024, nullptr, nullptr, tcQ, tsQ);
  gemm_mfma<EPI_XPOS><<<dim3(8, 32), 256, 0, stream>>>(hbuf, 1024, WkT, 1024, Kx, 1024, 1024, nullptr, nullptr, tcK, tsK);
  gemm_mfma<EPI_BF16><<<dim3(32, 16), 256, 0, stream>>>(WvT, 1024, hbuf, 1024, VTb, 4096, 1024, nullptr, nullptr, nullptr, nullptr);
  gemm_mfma<EPI_GATE><<<dim3(16, 32), 256, 0, stream>>>(hbuf, 1024, WgT, 1024, Gg, 2048, 1024, nullptr, nullptr, nullptr, nullptr);
  retention_mfma<<<dim3(32, 8, 2), 256, 0, stream>>>(Qx, Kx, VTb, Gg, gnw, gnb, GoutB);
  gemm_mfma<EPI_F32_RES><<<dim3(8, 32), 256, 0, stream>>>(GoutB, 2048, WoT, 2048, out, 1024, 2048, nullptr, X, nullptr, nullptr);

  // ---- block 2: cross retention (K/V from raw mem) ----
  cvt_bf16<<<2048, 256, 0, stream>>>(mem, mem16, 524288);
  ln_bf16<<<RTOT, 256, 0, stream>>>(out, ln2w, ln2b, hbuf);
  gemm_mfma<EPI_XPOS><<<dim3(8, 32), 256, 0, stream>>>(hbuf, 1024, cWqT, 1024, Qx, 1024, 1024, nullptr, nullptr, tcQ, tsQ);
  gemm_mfma<EPI_XPOS><<<dim3(8, 32), 256, 0, stream>>>(mem16, 1024, cWkT, 1024, Kx, 1024, 1024, nullptr, nullptr, tcK, tsK);
  gemm_mfma<EPI_BF16><<<dim3(32, 16), 256, 0, stream>>>(cWvT, 1024, mem16, 1024, VTb, 4096, 1024, nullptr, nullptr, nullptr, nullptr);
  gemm_mfma<EPI_GATE><<<dim3(16, 32), 256, 0, stream>>>(hbuf, 1024, cWgT, 1024, Gg, 2048, 1024, nullptr, nullptr, nullptr, nullptr);
  retention_mfma<<<dim3(32, 8, 2), 256, 0, stream>>>(Qx, Kx, VTb, Gg, cgnw, cgnb, GoutB);
  gemm_mfma<EPI_F32_RES><<<dim3(8, 32), 256, 0, stream>>>(GoutB, 2048, cWoT, 2048, out, 1024, 2048, nullptr, out, nullptr, nullptr);

  // ---- FFN ----
  transpose_bf16<<<dim3(32, 128, 1), 256, 0, stream>>>(W1, W1T, 1024, 4096);
  transpose_bf16<<<dim3(128, 32, 1), 256, 0, stream>>>(W2, W2T, 4096, 1024);
  ln_bf16<<<RTOT, 256, 0, stream>>>(out, ln2w, ln2b, hbuf);
  gemm_mfma<EPI_GELU><<<dim3(32, 32), 256, 0, stream>>>(hbuf, 1024, W1T, 1024, Tb, 4096, 1024, b1, nullptr, nullptr, nullptr);
  gemm_mfma<EPI_BRES><<<dim3(8, 32), 256, 0, stream>>>(Tb, 4096, W2T, 4096, out, 1024, 4096, b2, out, nullptr, nullptr);
}

// Round 3
// 717.761 us; speedup vs baseline: 7.7056x; 1.0439x over previous
//
#include <hip/hip_runtime.h>
#include <math.h>

// Problem: B=2, S=2048, d=1024, h=8, hd=128, hv=256, vd=2048, f=4096
#define RTOT 4096
#define SEQQ 2048

typedef unsigned int uint32;
typedef __attribute__((ext_vector_type(4))) float f32x4;
typedef __attribute__((ext_vector_type(8))) short bf16x8;

__device__ __forceinline__ unsigned short f2bf(float f) {
  unsigned int u = __float_as_uint(f);
  u = (u + 0x7FFFu + ((u >> 16) & 1u)) >> 16;
  return (unsigned short)u;
}
__device__ __forceinline__ float bf2f(unsigned short h) {
  return __uint_as_float(((unsigned int)h) << 16);
}
__device__ __forceinline__ void gld16(const void* g, void* l) {
  __builtin_amdgcn_global_load_lds(
      (const __attribute__((address_space(1))) uint32*)g,
      (__attribute__((address_space(3))) uint32*)l, 16, 0, 0);
}

// ---------------- tiled transpose f32[R][C] -> bf16[C][R], batched z ----------
__global__ __launch_bounds__(256) void transpose_bf16(
    const float* __restrict__ in, unsigned short* __restrict__ out, int R, int C) {
  __shared__ float t[32][33];
  int z = blockIdx.z;
  in  += (size_t)z * R * C;
  out += (size_t)z * C * R;
  int r0 = blockIdx.x * 32, c0 = blockIdx.y * 32;
  int tx = threadIdx.x & 31, ty = threadIdx.x >> 5;
  #pragma unroll
  for (int i = 0; i < 4; ++i) {
    int r = ty + i * 8;
    t[r][tx] = in[(size_t)(r0 + r) * C + c0 + tx];
  }
  __syncthreads();
  #pragma unroll
  for (int i = 0; i < 4; ++i) {
    int c = ty + i * 8;
    out[(size_t)(c0 + c) * R + r0 + tx] = f2bf(t[tx][c]);
  }
}

// ---------------- f32 -> bf16 convert ----------------
__global__ __launch_bounds__(256) void cvt_bf16(
    const float* __restrict__ in, unsigned short* __restrict__ out, int n8) {
  int i = blockIdx.x * 256 + threadIdx.x;
  if (i >= n8) return;
  const float4* p = (const float4*)(in + (size_t)i * 8);
  float4 a = p[0], b = p[1];
  bf16x8 v;
  v[0] = (short)f2bf(a.x); v[1] = (short)f2bf(a.y); v[2] = (short)f2bf(a.z); v[3] = (short)f2bf(a.w);
  v[4] = (short)f2bf(b.x); v[5] = (short)f2bf(b.y); v[6] = (short)f2bf(b.z); v[7] = (short)f2bf(b.w);
  *(bf16x8*)(out + (size_t)i * 8) = v;
}

// ---------------- xpos coefficient tables [4][2048*64] f32 -------------------
__global__ __launch_bounds__(256) void tabgen(float* __restrict__ tab) {
  int i = blockIdx.x * 256 + threadIdx.x;   // 131072
  int pos = i >> 6, j = i & 63;
  float bs = (2.f * (float)j + 51.2f) * (1.f / 179.2f);
  float e = (float)pos * (1.f / 512.f);
  float sc = exp2f(e * log2f(bs));
  float invf = exp2f(-(float)j * (13.287712379549449f / 64.f));
  float su, cu;
  sincosf((float)pos * invf, &su, &cu);
  tab[i]            = cu * sc;   // cosQ
  tab[131072 + i]   = su * sc;   // sinQ
  float si = 1.f / sc;
  tab[262144 + i]   = cu * si;   // cosK
  tab[393216 + i]   = su * si;   // sinK
}

// ---------------- LayerNorm -> bf16 ----------------
__global__ __launch_bounds__(256) void ln_bf16(const float* __restrict__ x,
    const float* __restrict__ w, const float* __restrict__ b,
    unsigned short* __restrict__ out) {
  int row = blockIdx.x, tid = threadIdx.x;
  const float* xr = x + (size_t)row * 1024;
  float4 v = *(const float4*)(xr + tid * 4);
  float s  = v.x + v.y + v.z + v.w;
  float ss = v.x*v.x + v.y*v.y + v.z*v.z + v.w*v.w;
  #pragma unroll
  for (int o = 32; o > 0; o >>= 1) { s += __shfl_down(s, o); ss += __shfl_down(ss, o); }
  __shared__ float red[2][4];
  int wid = tid >> 6;
  if ((tid & 63) == 0) { red[0][wid] = s; red[1][wid] = ss; }
  __syncthreads();
  float st  = red[0][0] + red[0][1] + red[0][2] + red[0][3];
  float sst = red[1][0] + red[1][1] + red[1][2] + red[1][3];
  float mu   = st * (1.f / 1024.f);
  float var  = sst * (1.f / 1024.f) - mu * mu;
  float rstd = rsqrtf(var + 1e-5f);
  float4 wv = *(const float4*)(w + tid * 4);
  float4 bv = *(const float4*)(b + tid * 4);
  unsigned short o0 = f2bf((v.x - mu) * rstd * wv.x + bv.x);
  unsigned short o1 = f2bf((v.y - mu) * rstd * wv.y + bv.y);
  unsigned short o2 = f2bf((v.z - mu) * rstd * wv.z + bv.z);
  unsigned short o3 = f2bf((v.w - mu) * rstd * wv.w + bv.w);
  ushort4 o4 = make_ushort4(o0, o1, o2, o3);
  *(ushort4*)(out + (size_t)row * 1024 + tid * 4) = o4;
}

// ---------------- epilogues ----------------
enum { EPI_F32_RES = 0, EPI_BF16 = 1, EPI_XPOS = 2, EPI_GELU = 4, EPI_BRES = 5,
       EPI_QKG = 6, EPI_QG = 7 };

struct EpiP {
  void* C; int ldc;
  const float* bias; const float* resid;
  const float* tab;                       // xpos tables base (kernel-specific offset)
  unsigned short* oQ; unsigned short* oK; unsigned short* oG;
};

__device__ __forceinline__ float xpos_rot(float v, int m, int n,
                                          const float* tc, const float* ts) {
  float p = __shfl_xor(v, 1);
  int j = (n & 127) >> 1;
  int pos = m & (SEQQ - 1);
  float c = tc[pos * 64 + j], s = ts[pos * 64 + j];
  return (n & 1) ? (v * c + p * s) : (v * c - p * s);
}

template<int EPI>
__device__ __forceinline__ void epi_store(size_t m, int n, int N0, float v, const EpiP& P) {
  if constexpr (EPI == EPI_BF16) {
    ((unsigned short*)P.C)[m * P.ldc + n] = f2bf(v);
  } else if constexpr (EPI == EPI_XPOS) {
    v = xpos_rot(v, (int)m, n, P.tab, P.tab + 131072);
    ((unsigned short*)P.C)[m * P.ldc + n] = f2bf(v);
  } else if constexpr (EPI == EPI_GELU) {
    v += P.bias[n];
    v = 0.5f * v * (1.f + erff(v * 0.70710678f));
    ((unsigned short*)P.C)[m * P.ldc + n] = f2bf(v);
  } else if constexpr (EPI == EPI_BRES) {
    v += P.bias[n] + P.resid[m * P.ldc + n];
    ((float*)P.C)[m * P.ldc + n] = v;
  } else if constexpr (EPI == EPI_QKG) {
    if (N0 < 1024) {
      v = xpos_rot(v, (int)m, n, P.tab, P.tab + 131072);
      P.oQ[m * 1024 + n] = f2bf(v);
    } else if (N0 < 2048) {
      int nl = n - 1024;
      v = xpos_rot(v, (int)m, nl, P.tab + 262144, P.tab + 393216);
      P.oK[m * 1024 + nl] = f2bf(v);
    } else {
      int nl = n - 2048;
      P.oG[m * 2048 + nl] = f2bf(v / (1.f + expf(-v)));
    }
  } else if constexpr (EPI == EPI_QG) {
    if (N0 < 1024) {
      v = xpos_rot(v, (int)m, n, P.tab, P.tab + 131072);
      P.oQ[m * 1024 + n] = f2bf(v);
    } else {
      int nl = n - 1024;
      P.oG[m * 2048 + nl] = f2bf(v / (1.f + expf(-v)));
    }
  } else {  // EPI_F32_RES
    v += P.resid[m * P.ldc + n];
    ((float*)P.C)[m * P.ldc + n] = v;
  }
}

// ---------------- MFMA GEMM 128x128: C = A[M][K] * Bt[N][K]^T ----------------
template<int EPI>
__global__ __launch_bounds__(256) void gemm_mfma(
    const unsigned short* __restrict__ A, int lda,
    const unsigned short* __restrict__ Bt, int ldb, int K, EpiP P) {
  __shared__ __align__(16) unsigned short As[128 * 32];
  __shared__ __align__(16) unsigned short Bs[128 * 32];
  const int tid = threadIdx.x, w = tid >> 6, lane = tid & 63;
  const int M0 = blockIdx.y * 128, N0 = blockIdx.x * 128;
  const int fr = lane & 15, fs = lane >> 4;
  const int srow = lane >> 2, sp = lane & 3;

  f32x4 zf = {0.f, 0.f, 0.f, 0.f};
  f32x4 acc[4][4];
  #pragma unroll
  for (int i = 0; i < 4; ++i)
    #pragma unroll
    for (int j = 0; j < 4; ++j) acc[i][j] = zf;

  for (int k0 = 0; k0 < K; k0 += 32) {
    __syncthreads();
    #pragma unroll
    for (int c = 0; c < 4; ++c) {
      int ch = w * 4 + c;
      int cc = ch & 7;
      int row = cc * 16 + srow;
      int so = sp ^ ((row >> 1) & 3);
      if (ch < 8) gld16(A  + (size_t)(M0 + row) * lda + k0 + so * 8, As + cc * 512);
      else        gld16(Bt + (size_t)(N0 + row) * ldb + k0 + so * 8, Bs + cc * 512);
    }
    __syncthreads();
    bf16x8 af[4], bfr[4];
    #pragma unroll
    for (int mi = 0; mi < 4; ++mi) {
      int row = (w >> 1) * 64 + mi * 16 + fr;
      af[mi] = *(const bf16x8*)(As + row * 32 + (fs ^ ((row >> 1) & 3)) * 8);
    }
    #pragma unroll
    for (int ni = 0; ni < 4; ++ni) {
      int row = (w & 1) * 64 + ni * 16 + fr;
      bfr[ni] = *(const bf16x8*)(Bs + row * 32 + (fs ^ ((row >> 1) & 3)) * 8);
    }
    #pragma unroll
    for (int mi = 0; mi < 4; ++mi)
      #pragma unroll
      for (int ni = 0; ni < 4; ++ni)
        acc[mi][ni] = __builtin_amdgcn_mfma_f32_16x16x32_bf16(af[mi], bfr[ni], acc[mi][ni], 0, 0, 0);
  }

  #pragma unroll
  for (int mi = 0; mi < 4; ++mi)
    #pragma unroll
    for (int r = 0; r < 4; ++r) {
      size_t m = M0 + (w >> 1) * 64 + mi * 16 + fs * 4 + r;
      #pragma unroll
      for (int ni = 0; ni < 4; ++ni) {
        int n = N0 + (w & 1) * 64 + ni * 16 + fr;
        epi_store<EPI>(m, n, N0, acc[mi][ni][r], P);
      }
    }
}

// ---------------- MFMA GEMM 128x64 (for N=1024 shapes): better occupancy ----
template<int EPI>
__global__ __launch_bounds__(256) void gemm_bn64(
    const unsigned short* __restrict__ A, int lda,
    const unsigned short* __restrict__ Bt, int ldb, int K, EpiP P) {
  __shared__ __align__(16) unsigned short As[128 * 32];
  __shared__ __align__(16) unsigned short Bs[64 * 32];
  const int tid = threadIdx.x, w = tid >> 6, lane = tid & 63;
  const int M0 = blockIdx.y * 128, N0 = blockIdx.x * 64;
  const int fr = lane & 15, fs = lane >> 4;
  const int srow = lane >> 2, sp = lane & 3;

  f32x4 zf = {0.f, 0.f, 0.f, 0.f};
  f32x4 acc[2][4];
  #pragma unroll
  for (int i = 0; i < 2; ++i)
    #pragma unroll
    for (int j = 0; j < 4; ++j) acc[i][j] = zf;

  for (int k0 = 0; k0 < K; k0 += 32) {
    __syncthreads();
    #pragma unroll
    for (int c = 0; c < 3; ++c) {
      int ch = w * 3 + c;                  // 12 chunks: 8 A + 4 B
      if (ch < 8) {
        int row = ch * 16 + srow;
        int so = sp ^ ((row >> 1) & 3);
        gld16(A + (size_t)(M0 + row) * lda + k0 + so * 8, As + ch * 512);
      } else {
        int bch = ch - 8;
        int row = bch * 16 + srow;
        int so = sp ^ ((row >> 1) & 3);
        gld16(Bt + (size_t)(N0 + row) * ldb + k0 + so * 8, Bs + bch * 512);
      }
    }
    __syncthreads();
    bf16x8 af[2], bfr[4];
    #pragma unroll
    for (int mi = 0; mi < 2; ++mi) {
      int row = w * 32 + mi * 16 + fr;
      af[mi] = *(const bf16x8*)(As + row * 32 + (fs ^ ((row >> 1) & 3)) * 8);
    }
    #pragma unroll
    for (int ni = 0; ni < 4; ++ni) {
      int row = ni * 16 + fr;
      bfr[ni] = *(const bf16x8*)(Bs + row * 32 + (fs ^ ((row >> 1) & 3)) * 8);
    }
    #pragma unroll
    for (int mi = 0; mi < 2; ++mi)
      #pragma unroll
      for (int ni = 0; ni < 4; ++ni)
        acc[mi][ni] = __builtin_amdgcn_mfma_f32_16x16x32_bf16(af[mi], bfr[ni], acc[mi][ni], 0, 0, 0);
  }

  #pragma unroll
  for (int mi = 0; mi < 2; ++mi)
    #pragma unroll
    for (int r = 0; r < 4; ++r) {
      size_t m = M0 + w * 32 + mi * 16 + fs * 4 + r;
      #pragma unroll
      for (int ni = 0; ni < 4; ++ni) {
        int n = N0 + ni * 16 + fr;
        epi_store<EPI>(m, n, N0, acc[mi][ni][r], P);
      }
    }
}

// ---------------- MFMA retention: Y=(QK^T*D)V fused with groupnorm+gate -----
// 1D grid of 512; pairing (i, i+256) balances long+short qtiles on a CU.
__global__ __launch_bounds__(256) void retention_mfma(
    const unsigned short* __restrict__ Qx, const unsigned short* __restrict__ Kx,
    const unsigned short* __restrict__ VT, const unsigned short* __restrict__ Gate,
    const float* __restrict__ gnw, const float* __restrict__ gnb,
    unsigned short* __restrict__ Gout) {
  __shared__ __align__(16) unsigned short Ks[32 * 128];   // [32 t][128 e], swz
  __shared__ __align__(16) unsigned short Vs[256 * 32];   // [256 v][32 t], swz
  __shared__ __align__(16) float Ps[4][16 * 36];
  const int tid = threadIdx.x, w = tid >> 6, lane = tid & 63;
  int bid = blockIdx.x, qt, h, b;
  if (bid < 256) { qt = 31 - (bid >> 3); h = bid & 7; b = 0; }
  else           { int k = bid - 256; qt = k >> 3; h = k & 7; b = 1; }
  const int q0 = qt * 64;
  const int fr = lane & 15, fs = lane >> 4;

  float gamma = 1.f - expf(-3.4657359028f - 0.3960841032f * (float)h);
  float l2g = log2f(gamma);     // negative

  size_t qrow = (size_t)b * SEQQ + q0 + w * 16 + fr;
  bf16x8 qf[4];
  #pragma unroll
  for (int ks = 0; ks < 4; ++ks)
    qf[ks] = *(const bf16x8*)(Qx + qrow * 1024 + h * 128 + ks * 32 + fs * 8);

  // decay row-factors gamma^q (hoisted out of t-loop)
  float fqv[4];
  #pragma unroll
  for (int r = 0; r < 4; ++r)
    fqv[r] = exp2f((float)(q0 + w * 16 + fs * 4 + r) * l2g);

  f32x4 zf = {0.f, 0.f, 0.f, 0.f};
  f32x4 yacc[16];
  #pragma unroll
  for (int i = 0; i < 16; ++i) yacc[i] = zf;

  int cutoff = (int)(27.f / (-l2g));
  int t_start = q0 - cutoff;
  if (t_start < 0) t_start = 0;
  t_start &= ~31;
  size_t kbase = (size_t)b * SEQQ;

  for (int t0 = t_start; t0 < q0 + 64; t0 += 32) {
    __syncthreads();
    #pragma unroll
    for (int c = 0; c < 2; ++c) {
      int ch = w * 2 + c;
      int row = ch * 4 + (lane >> 4);
      int so = (lane & 15) ^ (row & 15);
      gld16(Kx + (kbase + t0 + row) * 1024 + h * 128 + so * 8, Ks + ch * 512);
    }
    #pragma unroll
    for (int c = 0; c < 4; ++c) {
      int ch = w * 4 + c;
      int vrow = ch * 16 + (lane >> 2);
      int so = (lane & 3) ^ ((vrow >> 1) & 3);
      gld16(VT + (size_t)(h * 256 + vrow) * RTOT + kbase + t0 + so * 8, Vs + ch * 512);
    }
    __syncthreads();

    f32x4 sacc[2];
    sacc[0] = zf; sacc[1] = zf;
    #pragma unroll
    for (int nt = 0; nt < 2; ++nt) {
      int row = nt * 16 + fr;
      #pragma unroll
      for (int ks = 0; ks < 4; ++ks) {
        int sl = ks * 4 + fs;
        bf16x8 kf = *(const bf16x8*)(Ks + row * 128 + (sl ^ (row & 15)) * 8);
        sacc[nt] = __builtin_amdgcn_mfma_f32_16x16x32_bf16(qf[ks], kf, sacc[nt], 0, 0, 0);
      }
    }
    // decay (gamma^q * gamma^-t) + causal mask -> per-wave P LDS
    float ftv[2];
    ftv[0] = exp2f((float)(t0 + fr)      * -l2g);
    ftv[1] = exp2f((float)(t0 + 16 + fr) * -l2g);
    float* Pw = Ps[w];
    #pragma unroll
    for (int nt = 0; nt < 2; ++nt) {
      #pragma unroll
      for (int r = 0; r < 4; ++r) {
        int sl_ = fs * 4 + r;
        int diff = (q0 + w * 16 + sl_) - (t0 + nt * 16 + fr);
        float v = (diff >= 0) ? sacc[nt][r] * (fqv[r] * ftv[nt]) : 0.f;
        Pw[sl_ * 36 + nt * 16 + fr] = v;
      }
    }
    f32x4 pa = *(const f32x4*)(Pw + fr * 36 + fs * 8);
    f32x4 pb = *(const f32x4*)(Pw + fr * 36 + fs * 8 + 4);
    bf16x8 pf;
    pf[0] = (short)f2bf(pa[0]); pf[1] = (short)f2bf(pa[1]);
    pf[2] = (short)f2bf(pa[2]); pf[3] = (short)f2bf(pa[3]);
    pf[4] = (short)f2bf(pb[0]); pf[5] = (short)f2bf(pb[1]);
    pf[6] = (short)f2bf(pb[2]); pf[7] = (short)f2bf(pb[3]);
    #pragma unroll
    for (int nv = 0; nv < 16; ++nv) {
      int vrow = nv * 16 + fr;
      bf16x8 vf = *(const bf16x8*)(Vs + vrow * 32 + (fs ^ ((vrow >> 1) & 3)) * 8);
      yacc[nv] = __builtin_amdgcn_mfma_f32_16x16x32_bf16(pf, vf, yacc[nv], 0, 0, 0);
    }
  }

  // epilogue: groupnorm over 256 v * affine * silu(gate) -> bf16 Gout
  #pragma unroll
  for (int r = 0; r < 4; ++r) {
    float s = 0.f, sq = 0.f;
    #pragma unroll
    for (int nv = 0; nv < 16; ++nv) { float v = yacc[nv][r]; s += v; sq += v * v; }
    #pragma unroll
    for (int msk = 1; msk < 16; msk <<= 1) { s += __shfl_xor(s, msk); sq += __shfl_xor(sq, msk); }
    float mu = s * (1.f / 256.f);
    float var = sq * (1.f / 256.f) - mu * mu;
    float rstd = rsqrtf(var + 1e-5f);
    int srow = q0 + w * 16 + fs * 4 + r;
    size_t mrow = (size_t)b * SEQQ + srow;
    const unsigned short* grow = Gate + mrow * 2048 + h * 256;
    unsigned short* orow = Gout + mrow * 2048 + h * 256;
    #pragma unroll
    for (int nv = 0; nv < 16; ++nv) {
      int col = nv * 16 + fr;
      float yn = (yacc[nv][r] - mu) * rstd * gnw[h * 256 + col] + gnb[h * 256 + col];
      orow[col] = f2bf(bf2f(grow[col]) * yn);
    }
  }
}

// =============================== host ========================================
extern "C" void kernel_launch(void* const* d_in, const int* in_sizes, int n_in,
                              void* d_out, int out_size, void* d_ws, size_t ws_size,
                              hipStream_t stream) {
  const float* X    = (const float*)d_in[0];
  const float* mem  = (const float*)d_in[1];
  const float* ln1w = (const float*)d_in[2];
  const float* ln1b = (const float*)d_in[3];
  const float* ln2w = (const float*)d_in[4];
  const float* ln2b = (const float*)d_in[5];
  const float* Wq   = (const float*)d_in[6];
  const float* Wk   = (const float*)d_in[7];
  const float* Wv   = (const float*)d_in[8];
  const float* Wg   = (const float*)d_in[9];
  const float* Wo   = (const float*)d_in[10];
  const float* gnw  = (const float*)d_in[11];
  const float* gnb  = (const float*)d_in[12];
  const float* cWq  = (const float*)d_in[13];
  const float* cWk  = (const float*)d_in[14];
  const float* cWv  = (const float*)d_in[15];
  const float* cWg  = (const float*)d_in[16];
  const float* cWo  = (const float*)d_in[17];
  const float* cgnw = (const float*)d_in[18];
  const float* cgnb = (const float*)d_in[19];
  const float* W1   = (const float*)d_in[20];
  const float* b1   = (const float*)d_in[21];
  const float* W2   = (const float*)d_in[22];
  const float* b2   = (const float*)d_in[23];
  float* out = (float*)d_out;

  const size_t MB = 1024ull * 1024ull;
  if (ws_size < 106 * MB) return;
  unsigned char* W8 = (unsigned char*)d_ws;
  unsigned short* WqkgT = (unsigned short*)(W8 + 0 * MB);   // 8MB [4096][1024]
  unsigned short* WvT   = (unsigned short*)(W8 + 8 * MB);   // 4MB [2048][1024]
  unsigned short* WoT   = (unsigned short*)(W8 + 12 * MB);  // 4MB [1024][2048]
  unsigned short* cQGT  = (unsigned short*)(W8 + 16 * MB);  // 6MB [3072][1024]
  unsigned short* cWkT  = (unsigned short*)(W8 + 22 * MB);  // 2MB
  unsigned short* cWvT  = (unsigned short*)(W8 + 24 * MB);  // 4MB
  unsigned short* cWoT  = (unsigned short*)(W8 + 28 * MB);  // 4MB
  float*          tab   = (float*)(W8 + 32 * MB);           // 2MB
  unsigned short* hbuf  = (unsigned short*)(W8 + 34 * MB);  // 8MB
  unsigned short* Qx    = (unsigned short*)(W8 + 42 * MB);  // 8MB (later W1T)
  unsigned short* Kx    = (unsigned short*)(W8 + 50 * MB);  // 8MB (later W2T)
  unsigned short* W1T   = Qx;
  unsigned short* W2T   = Kx;
  unsigned short* VTb   = (unsigned short*)(W8 + 58 * MB);  // 16MB
  unsigned short* Gg    = (unsigned short*)(W8 + 74 * MB);  // 16MB
  unsigned short* Tb    = VTb;                               // FFN mid 32MB
  unsigned short* GoutB = (unsigned short*)(W8 + 90 * MB);  // 16MB
  unsigned short* mem16 = GoutB;                             // 8MB overlay

  // ---- weight prep ----
  transpose_bf16<<<dim3(32, 4, 8),  256, 0, stream>>>(Wq,  WqkgT,               1024, 128);
  transpose_bf16<<<dim3(32, 4, 8),  256, 0, stream>>>(Wk,  WqkgT + 1024 * 1024, 1024, 128);
  transpose_bf16<<<dim3(32, 64, 1), 256, 0, stream>>>(Wg,  WqkgT + 2048 * 1024, 1024, 2048);
  transpose_bf16<<<dim3(32, 8, 8),  256, 0, stream>>>(Wv,  WvT,  1024, 256);
  transpose_bf16<<<dim3(64, 32, 1), 256, 0, stream>>>(Wo,  WoT,  2048, 1024);
  transpose_bf16<<<dim3(32, 4, 8),  256, 0, stream>>>(cWq, cQGT,               1024, 128);
  transpose_bf16<<<dim3(32, 64, 1), 256, 0, stream>>>(cWg, cQGT + 1024 * 1024, 1024, 2048);
  transpose_bf16<<<dim3(32, 4, 8),  256, 0, stream>>>(cWk, cWkT, 1024, 128);
  transpose_bf16<<<dim3(32, 8, 8),  256, 0, stream>>>(cWv, cWvT, 1024, 256);
  transpose_bf16<<<dim3(64, 32, 1), 256, 0, stream>>>(cWo, cWoT, 2048, 1024);
  tabgen<<<512, 256, 0, stream>>>(tab);

  EpiP P{};

  // ---- block 1: self retention ----
  ln_bf16<<<RTOT, 256, 0, stream>>>(X, ln1w, ln1b, hbuf);
  P = EpiP{nullptr, 0, nullptr, nullptr, tab, Qx, Kx, Gg};
  gemm_mfma<EPI_QKG><<<dim3(32, 32), 256, 0, stream>>>(hbuf, 1024, WqkgT, 1024, 1024, P);
  P = EpiP{VTb, 4096, nullptr, nullptr, nullptr, nullptr, nullptr, nullptr};
  gemm_mfma<EPI_BF16><<<dim3(32, 16), 256, 0, stream>>>(WvT, 1024, hbuf, 1024, 1024, P);
  retention_mfma<<<dim3(512), 256, 0, stream>>>(Qx, Kx, VTb, Gg, gnw, gnb, GoutB);
  P = EpiP{out, 1024, nullptr, X, nullptr, nullptr, nullptr, nullptr};
  gemm_bn64<EPI_F32_RES><<<dim3(16, 32), 256, 0, stream>>>(GoutB, 2048, WoT, 2048, 2048, P);

  // ---- block 2: cross retention ----
  cvt_bf16<<<2048, 256, 0, stream>>>(mem, mem16, 524288);
  ln_bf16<<<RTOT, 256, 0, stream>>>(out, ln2w, ln2b, hbuf);
  P = EpiP{nullptr, 0, nullptr, nullptr, tab, Qx, nullptr, Gg};
  gemm_mfma<EPI_QG><<<dim3(24, 32), 256, 0, stream>>>(hbuf, 1024, cQGT, 1024, 1024, P);
  P = EpiP{Kx, 1024, nullptr, nullptr, tab + 262144, nullptr, nullptr, nullptr};
  gemm_bn64<EPI_XPOS><<<dim3(16, 32), 256, 0, stream>>>(mem16, 1024, cWkT, 1024, 1024, P);
  P = EpiP{VTb, 4096, nullptr, nullptr, nullptr, nullptr, nullptr, nullptr};
  gemm_mfma<EPI_BF16><<<dim3(32, 16), 256, 0, stream>>>(cWvT, 1024, mem16, 1024, 1024, P);
  retention_mfma<<<dim3(512), 256, 0, stream>>>(Qx, Kx, VTb, Gg, cgnw, cgnb, GoutB);
  P = EpiP{out, 1024, nullptr, out, nullptr, nullptr, nullptr, nullptr};
  gemm_bn64<EPI_F32_RES><<<dim3(16, 32), 256, 0, stream>>>(GoutB, 2048, cWoT, 2048, 2048, P);

  // ---- FFN ----
  transpose_bf16<<<dim3(32, 128, 1), 256, 0, stream>>>(W1, W1T, 1024, 4096);
  transpose_bf16<<<dim3(128, 32, 1), 256, 0, stream>>>(W2, W2T, 4096, 1024);
  ln_bf16<<<RTOT, 256, 0, stream>>>(out, ln2w, ln2b, hbuf);
  P = EpiP{Tb, 4096, b1, nullptr, nullptr, nullptr, nullptr, nullptr};
  gemm_mfma<EPI_GELU><<<dim3(32, 32), 256, 0, stream>>>(hbuf, 1024, W1T, 1024, 1024, P);
  P = EpiP{out, 1024, b2, out, nullptr, nullptr, nullptr, nullptr};
  gemm_bn64<EPI_BRES><<<dim3(16, 32), 256, 0, stream>>>(Tb, 4096, W2T, 4096, 4096, P);
}